// Round 1
// baseline (757.054 us; speedup 1.0000x reference)
//
#include <hip/hip_runtime.h>

typedef short bf16x8 __attribute__((ext_vector_type(8)));
typedef float floatx4 __attribute__((ext_vector_type(4)));

// ---------- bf16 helpers (bit-level, RNE) ----------
__device__ __forceinline__ float bf2f(unsigned short u) {
    return __uint_as_float(((unsigned)u) << 16);
}
__device__ __forceinline__ unsigned short f2bf(float f) {
    unsigned u = __float_as_uint(f);
    unsigned rnd = 0x7fffu + ((u >> 16) & 1u);
    return (unsigned short)((u + rnd) >> 16);
}

// ---------- async global->LDS 16B ----------
__device__ __forceinline__ void async16(const unsigned short* g, unsigned short* l) {
    __builtin_amdgcn_global_load_lds(
        (const __attribute__((address_space(1))) unsigned int*)g,
        (__attribute__((address_space(3))) unsigned int*)l,
        16, 0, 0);
}

// ---------- fp32 -> bf16 batch convert ----------
struct CvtArgs {
    const float* src[12];
    unsigned short* dst[12];
    int n4[12];
};

__global__ __launch_bounds__(256) void cvt_kernel(CvtArgs a) {
    int t = blockIdx.y;
    int n4 = a.n4[t];
    const float4* s = (const float4*)a.src[t];
    unsigned short* d = a.dst[t];
    int stride = gridDim.x * blockDim.x;
    for (int i = blockIdx.x * blockDim.x + threadIdx.x; i < n4; i += stride) {
        float4 v = s[i];
        ushort4 o;
        o.x = f2bf(v.x); o.y = f2bf(v.y); o.z = f2bf(v.z); o.w = f2bf(v.w);
        ((ushort4*)d)[i] = o;
    }
}

// ---------- GEMM: C[M,N] = A[M,K] @ B[N,K]^T * scale (+ bias[N]) ----------
// A, B bf16 row-major. BF16_OUT: store bf16 else fp32. TRANS_OUT: store C^T ([N,M], bf16 only).
// 128x128 block tile, BK=32, 4 waves (2x2), each wave 64x64 via 4x4 MFMA 16x16x32.
// LDS tiles stored in MFMA fragment order: position p in [0,512) holds
// X[i*16 + r][k0 + q*8 .. +7] where i=p>>6, q=(p>>4)&3, r=p&15.  This makes both
// the global_load_lds staging (base + lane*16) and the ds_read_b128 fragment
// reads lane-linear -> no bank conflicts.
template<bool BF16_OUT, bool TRANS_OUT, bool HAS_BIAS>
__global__ __launch_bounds__(256, 2) void gemm_bt(
    const unsigned short* __restrict__ A,
    const unsigned short* __restrict__ B,
    const float* __restrict__ bias,
    void* __restrict__ C,
    int M, int N, int K, float scale)
{
    constexpr int BM = 128, BN = 128, BK = 32;
    __shared__ __align__(16) unsigned short lA[BM * BK];
    __shared__ __align__(16) unsigned short lB[BN * BK];

    const int tid  = threadIdx.x;
    const int lane = tid & 63;
    const int wave = tid >> 6;
    const int wm   = wave >> 1;   // 0..1
    const int wn   = wave & 1;    // 0..1
    const int quad = lane >> 4;   // 0..3
    const int r16  = lane & 15;

    const int row0 = blockIdx.y * BM;
    const int col0 = blockIdx.x * BN;

    floatx4 acc[4][4] = {};

    // staging decode: chunk positions p0 = tid, p1 = 256 + tid
    const int p0 = tid, p1 = 256 + tid;
    const int i0 = p0 >> 6, q0 = (p0 >> 4) & 3, r0 = p0 & 15;
    const int i1 = p1 >> 6, q1 = (p1 >> 4) & 3, r1 = p1 & 15;

    const unsigned short* gA0 = A + (size_t)(row0 + i0 * 16 + r0) * K + q0 * 8;
    const unsigned short* gA1 = A + (size_t)(row0 + i1 * 16 + r1) * K + q1 * 8;
    const unsigned short* gB0 = B + (size_t)(col0 + i0 * 16 + r0) * K + q0 * 8;
    const unsigned short* gB1 = B + (size_t)(col0 + i1 * 16 + r1) * K + q1 * 8;

    unsigned short* lA0 = lA + p0 * 8;
    unsigned short* lA1 = lA + p1 * 8;
    unsigned short* lB0 = lB + p0 * 8;
    unsigned short* lB1 = lB + p1 * 8;

    for (int k0 = 0; k0 < K; k0 += BK) {
        async16(gA0, lA0);
        async16(gA1, lA1);
        async16(gB0, lB0);
        async16(gB1, lB1);
        gA0 += BK; gA1 += BK; gB0 += BK; gB1 += BK;
        __syncthreads();

        bf16x8 af[4], bfr[4];
        #pragma unroll
        for (int i = 0; i < 4; i++)
            af[i] = *(const bf16x8*)(lA + ((wm * 4 + i) * 64 + lane) * 8);
        #pragma unroll
        for (int j = 0; j < 4; j++)
            bfr[j] = *(const bf16x8*)(lB + ((wn * 4 + j) * 64 + lane) * 8);

        #pragma unroll
        for (int i = 0; i < 4; i++)
            #pragma unroll
            for (int j = 0; j < 4; j++)
                acc[i][j] = __builtin_amdgcn_mfma_f32_16x16x32_bf16(
                    af[i], bfr[j], acc[i][j], 0, 0, 0);
        __syncthreads();
    }

    float bv[4];
    if (HAS_BIAS) {
        #pragma unroll
        for (int j = 0; j < 4; j++)
            bv[j] = bias[col0 + (wn * 4 + j) * 16 + r16];
    }

    #pragma unroll
    for (int i = 0; i < 4; i++) {
        const int m_base = row0 + (wm * 4 + i) * 16 + quad * 4;
        #pragma unroll
        for (int j = 0; j < 4; j++) {
            const int n = col0 + (wn * 4 + j) * 16 + r16;
            if (TRANS_OUT) {
                // C^T layout [N][M], bf16; 4 consecutive m -> one 8B store
                ushort4 o;
                float v0 = acc[i][j][0] * scale; if (HAS_BIAS) v0 += bv[j];
                float v1 = acc[i][j][1] * scale; if (HAS_BIAS) v1 += bv[j];
                float v2 = acc[i][j][2] * scale; if (HAS_BIAS) v2 += bv[j];
                float v3 = acc[i][j][3] * scale; if (HAS_BIAS) v3 += bv[j];
                o.x = f2bf(v0); o.y = f2bf(v1); o.z = f2bf(v2); o.w = f2bf(v3);
                *(ushort4*)((unsigned short*)C + (size_t)n * M + m_base) = o;
            } else {
                #pragma unroll
                for (int r = 0; r < 4; r++) {
                    float v = acc[i][j][r] * scale;
                    if (HAS_BIAS) v += bv[j];
                    size_t off = (size_t)(m_base + r) * N + n;
                    if (BF16_OUT) ((unsigned short*)C)[off] = f2bf(v);
                    else          ((float*)C)[off] = v;
                }
            }
        }
    }
}

// ---------- row softmax: S[row,0..4095] bf16 -> P bf16, fp32 math ----------
__global__ __launch_bounds__(256) void softmax_kernel(
    const unsigned short* __restrict__ S, unsigned short* __restrict__ P)
{
    const int N = 4096;
    const int row = blockIdx.x;
    const int tid = threadIdx.x;
    const int lane = tid & 63;
    const int wave = tid >> 6;

    const bf16x8* src = (const bf16x8*)(S + (size_t)row * N);
    bf16x8 c0 = src[2 * tid];
    bf16x8 c1 = src[2 * tid + 1];

    float x[16];
    #pragma unroll
    for (int k = 0; k < 8; k++) {
        x[k]     = bf2f((unsigned short)c0[k]);
        x[8 + k] = bf2f((unsigned short)c1[k]);
    }

    float m = -3.4e38f;
    #pragma unroll
    for (int k = 0; k < 16; k++) m = fmaxf(m, x[k]);
    #pragma unroll
    for (int off = 32; off > 0; off >>= 1) m = fmaxf(m, __shfl_xor(m, off));

    __shared__ float redmax[4], redsum[4];
    if (lane == 0) redmax[wave] = m;
    __syncthreads();
    m = fmaxf(fmaxf(redmax[0], redmax[1]), fmaxf(redmax[2], redmax[3]));

    float s = 0.f;
    #pragma unroll
    for (int k = 0; k < 16; k++) { x[k] = __expf(x[k] - m); s += x[k]; }
    #pragma unroll
    for (int off = 32; off > 0; off >>= 1) s += __shfl_xor(s, off);
    if (lane == 0) redsum[wave] = s;
    __syncthreads();
    s = redsum[0] + redsum[1] + redsum[2] + redsum[3];
    const float inv = 1.0f / s;

    bf16x8 o0, o1;
    #pragma unroll
    for (int k = 0; k < 8; k++) {
        o0[k] = (short)f2bf(x[k] * inv);
        o1[k] = (short)f2bf(x[8 + k] * inv);
    }
    bf16x8* dst = (bf16x8*)(P + (size_t)row * N);
    dst[2 * tid]     = o0;
    dst[2 * tid + 1] = o1;
}

// ---------- launch ----------
extern "C" void kernel_launch(void* const* d_in, const int* in_sizes, int n_in,
                              void* d_out, int out_size, void* d_ws, size_t ws_size,
                              hipStream_t stream) {
    (void)in_sizes; (void)n_in; (void)out_size;
    const int NC = 4096, NP = 4096, D = 1024;

    char* ws = (char*)d_ws;
    size_t off = 0;
    auto alloc = [&](size_t b) { size_t o = off; off += (b + 255) & ~(size_t)255; return o; };

    unsigned short* xb[6];
    for (int i = 0; i < 6; i++) xb[i] = (unsigned short*)(ws + alloc((size_t)NC * D * 2));
    unsigned short* wb[6];
    for (int i = 0; i < 6; i++) wb[i] = (unsigned short*)(ws + alloc((size_t)D * D * 2));
    unsigned short* qc  = (unsigned short*)(ws + alloc((size_t)NC * D * 2));
    unsigned short* kc  = (unsigned short*)(ws + alloc((size_t)NC * D * 2));
    unsigned short* qp  = (unsigned short*)(ws + alloc((size_t)NP * D * 2));
    unsigned short* kp  = (unsigned short*)(ws + alloc((size_t)NP * D * 2));
    unsigned short* vcT = (unsigned short*)(ws + alloc((size_t)NC * D * 2)); // [D][NC]
    unsigned short* vpT = (unsigned short*)(ws + alloc((size_t)NP * D * 2)); // [D][NP]
    unsigned short* Sb  = (unsigned short*)(ws + alloc((size_t)4096 * 4096 * 2));
    unsigned short* Pb  = (unsigned short*)(ws + alloc((size_t)4096 * 4096 * 2));

    if (ws_size < off) return; // workspace too small -> clean mismatch, not a fault

    // convert inputs (d_in[0..5]) and weights (d_in[6,8,10,12,14,16]) to bf16
    CvtArgs ca;
    for (int i = 0; i < 6; i++) {
        ca.src[i] = (const float*)d_in[i];
        ca.dst[i] = xb[i];
        ca.n4[i] = NC * D / 4;
    }
    const int widx[6] = {6, 8, 10, 12, 14, 16};
    for (int i = 0; i < 6; i++) {
        ca.src[6 + i] = (const float*)d_in[widx[i]];
        ca.dst[6 + i] = wb[i];
        ca.n4[6 + i] = D * D / 4;
    }
    cvt_kernel<<<dim3(256, 12), 256, 0, stream>>>(ca);

    const dim3 blk(256);
    auto grid = [](int M, int N) { return dim3(N / 128, M / 128); };
    const float inv_scale = 1.0f / 32.0f; // 1/sqrt(D_OUT)

    // projections: X @ W^T + b   (W is [d_out, d_in] = [N, K] already B^T form)
    gemm_bt<true, false, true><<<grid(NC, D), blk, 0, stream>>>(
        xb[0], wb[0], (const float*)d_in[7],  qc,  NC, D, D, 1.0f);
    gemm_bt<true, false, true><<<grid(NC, D), blk, 0, stream>>>(
        xb[1], wb[1], (const float*)d_in[9],  kc,  NC, D, D, 1.0f);
    gemm_bt<true, true,  true><<<grid(NC, D), blk, 0, stream>>>(
        xb[2], wb[2], (const float*)d_in[11], vcT, NC, D, D, 1.0f);
    gemm_bt<true, false, true><<<grid(NP, D), blk, 0, stream>>>(
        xb[3], wb[3], (const float*)d_in[13], qp,  NP, D, D, 1.0f);
    gemm_bt<true, false, true><<<grid(NP, D), blk, 0, stream>>>(
        xb[4], wb[4], (const float*)d_in[15], kp,  NP, D, D, 1.0f);
    gemm_bt<true, true,  true><<<grid(NP, D), blk, 0, stream>>>(
        xb[5], wb[5], (const float*)d_in[17], vpT, NP, D, D, 1.0f);

    float* out_c = (float*)d_out;                       // comp_fused [NC, D]
    float* out_p = (float*)d_out + (size_t)NC * D;      // prot_fused [NP, D]

    // side 1: compound attends protein
    gemm_bt<true, false, false><<<grid(NC, NP), blk, 0, stream>>>(
        qc, kp, nullptr, Sb, NC, NP, D, inv_scale);
    softmax_kernel<<<dim3(NC), blk, 0, stream>>>(Sb, Pb);
    gemm_bt<false, false, false><<<grid(NC, D), blk, 0, stream>>>(
        Pb, vpT, nullptr, out_c, NC, D, NP, 1.0f);

    // side 2: protein attends compound
    gemm_bt<true, false, false><<<grid(NP, NC), blk, 0, stream>>>(
        qp, kc, nullptr, Sb, NP, NC, D, inv_scale);
    softmax_kernel<<<dim3(NP), blk, 0, stream>>>(Sb, Pb);
    gemm_bt<false, false, false><<<grid(NP, D), blk, 0, stream>>>(
        Pb, vcT, nullptr, out_p, NP, D, NC, 1.0f);
}